// Round 6
// baseline (281.332 us; speedup 1.0000x reference)
//
#include <hip/hip_runtime.h>
#include <hip/hip_fp16.h>
#include <math.h>

#define HDIM   256
#define QLEN   64
#define NNUM   8
#define NOPS   9
#define NCOLS  16
#define TSTEPS 4

// op indices: SUM=0 COUNT=1 DIFF=2 GREATER=3 LESSER=4 AND=5 OR=6 ASSIGN=7 RESET=8

// ---- workspace layout (float offsets) ----
#define WS_LPIV 0
#define WS_GPIV 1
#define WS_ACOL 2            // [4][16]
#define WS_AOP  66           // [4][9]
#define WS_Q    112          // [256] final question RNN state q
#define WS_PQO  368          // [256] W_op[:, :256] @ q
#define WS_PQC  624          // [256] W_col[:, :256] @ q
#define WS_HS   880          // [8][256] hidden states at left_word_indices
#define WS_XP   2928         // [64][256] xproj
#define WS_AH   19312        // [256][9]  W_hist[:, :256] @ op_emb.T
#define WS_BH   21616        // [256][16] W_hist[:, 256:512] @ col_emb.T
#define WS_WH16 25712        // Wh as f16, fragment order (65536 halfs = 32768 f)
#define WS_M16  58480        // 3x 256x256 f16 (h-side of W_op/W_col/W_hist): 98304 floats
#define WS_PART 156784       // [NBLK_C][8] block partials (D0..3, N0..3)
#define NBLK_C  2048
#define PRE2_BLOCKS 409      // ceil(104704/256)

typedef _Float16 f16x8 __attribute__((ext_vector_type(8)));
typedef _Float16 f16x4 __attribute__((ext_vector_type(4)));
typedef float    f32x4 __attribute__((ext_vector_type(4)));

__device__ __forceinline__ float fast_tanh(float x) {
    return 1.0f - 2.0f / (__expf(2.0f * x) + 1.0f);
}

// ============================================================================
// Kernel A (part 1): what the RNN needs — xproj + FULL Wh f16 pack.
//  gid ranges:
//   [0, 16384)              xproj[t][j] = emb[q[t]] . Wx[j,:]
//   [16384, 49152)          Wh -> f16 fragment-order pack, 32768 dwords,
//                           ALL 256 rows (tile t=hidx>>12 in [0,16))
// ============================================================================
__global__ void precompute_kernel(const int* __restrict__ q,
                                  const float* __restrict__ emb,
                                  const float* __restrict__ Wx,
                                  const float* __restrict__ Wh,
                                  float* __restrict__ ws) {
    int gid = blockIdx.x * 256 + threadIdx.x;
    if (gid < QLEN * HDIM) {
        int t = gid >> 8, j = gid & 255;
        const float4* x4 = (const float4*)(emb + (size_t)q[t] * HDIM);
        const float4* w4 = (const float4*)(Wx + (size_t)j * HDIM);
        float s = 0.f;
        for (int k = 0; k < HDIM / 4; k++) {
            float4 a = x4[k], b = w4[k];
            s += a.x * b.x + a.y * b.y + a.z * b.z + a.w * b.w;
        }
        ws[WS_XP + t * HDIM + j] = s;
    } else {
        // Wh f16 pack: half-index = (((t*8+kk)*4+quad)*16+qr)*8 + e,
        // value = Wh[16*t+qr][kk*32 + quad*8 + e], t in [0,16) (ALL rows)
        int did = gid - QLEN * HDIM;       // [0, 32768) dwords
        int hidx = did * 2;
        int e = hidx & 7, qr = (hidx >> 3) & 15, quad = (hidx >> 7) & 3;
        int kk = (hidx >> 9) & 7, t = hidx >> 12;
        const float* src = Wh + (size_t)(16 * t + qr) * HDIM + kk * 32 + quad * 8 + e;
        float2 v = *(const float2*)src;
        ((__half2*)(ws + WS_WH16))[did] = __floats2half2_rn(v.x, v.y);
    }
}

// ============================================================================
// Kernel B1: block 0 = question RNN (round-5 one-barrier body, unchanged).
// Blocks 1..409 = AH/BH/M16 precompute (concurrent, disjoint ws regions).
// Blocks 410..2457 = NEW: Infinity-Cache warm of `table` — stream-read the
// 64 MB table on the otherwise-idle CUs during the ~35us serial RNN so the
// later table_kernel reads hit L3 instead of HBM. Pure reads + asm sink
// (keeps the loads live vs DCE); no semantic effect.
// ============================================================================
__global__ __launch_bounds__(256, 1) void rnn_kernel(
        float* __restrict__ ws,
        const int* __restrict__ lwi,
        const float* __restrict__ W_op,
        const float* __restrict__ W_col,
        const float* __restrict__ W_hist,
        const float* __restrict__ op_emb,
        const float* __restrict__ col_emb,
        const float* __restrict__ table,
        int rows) {
    if (blockIdx.x >= 1 + PRE2_BLOCKS) {
        // ---- L3 warm: stream table (cached loads, coalesced) ----
        int wid = blockIdx.x - 1 - PRE2_BLOCKS;          // 0..2047
        const f32x4* t4 = (const f32x4*)table;
        long n4 = (long)rows * (NCOLS / 4);
        f32x4 acc = {0.f, 0.f, 0.f, 0.f};
        for (long i = (long)wid * 256 + threadIdx.x; i < n4; i += (long)2048 * 256)
            acc += t4[i];
        asm volatile("" :: "v"(acc));                    // sink (no DCE)
        return;
    }
    if (blockIdx.x != 0) {
        // ---- fused precompute part 2 ----
        int gid = (blockIdx.x - 1) * 256 + threadIdx.x;
        if (gid < HDIM * NOPS) {
            int j = gid / NOPS, o = gid % NOPS;
            const float4* w4 = (const float4*)(W_hist + (size_t)j * (3 * HDIM));
            const float4* e4 = (const float4*)(op_emb + (size_t)o * HDIM);
            float s = 0.f;
            for (int k = 0; k < HDIM / 4; k++) {
                float4 a = w4[k], b = e4[k];
                s += a.x * b.x + a.y * b.y + a.z * b.z + a.w * b.w;
            }
            ws[WS_AH + gid] = s;
        } else if (gid < HDIM * NOPS + HDIM * NCOLS) {
            int idx = gid - HDIM * NOPS;
            int j = idx / NCOLS, c = idx % NCOLS;
            const float4* w4 = (const float4*)(W_hist + (size_t)j * (3 * HDIM) + HDIM);
            const float4* e4 = (const float4*)(col_emb + (size_t)c * HDIM);
            float s = 0.f;
            for (int k = 0; k < HDIM / 4; k++) {
                float4 a = w4[k], b = e4[k];
                s += a.x * b.x + a.y * b.y + a.z * b.z + a.w * b.w;
            }
            ws[WS_BH + idx] = s;
        } else if (gid < HDIM * NOPS + HDIM * NCOLS + 98304) {
            // M16 pack: mat m = did>>15, within-mat half-index = (i*256+j)*8+e
            int did = gid - (HDIM * NOPS + HDIM * NCOLS);
            int mat = did >> 15;
            int hidx = (did & 32767) * 2;
            int e = hidx & 7, j = (hidx >> 3) & 255, i = hidx >> 11;
            const float* src;
            if (mat == 0)      src = W_op   + (size_t)j * (2 * HDIM) + HDIM     + i * 8 + e;
            else if (mat == 1) src = W_col  + (size_t)j * (2 * HDIM) + HDIM     + i * 8 + e;
            else               src = W_hist + (size_t)j * (3 * HDIM) + 2 * HDIM + i * 8 + e;
            float2 v = *(const float2*)src;
            ((__half2*)(ws + WS_M16))[did] = __floats2half2_rn(v.x, v.y);
        }
        return;
    }

    // ---- block 0: the RNN (round-5 one-barrier body, unchanged) ----
    __shared__ float xpL[QLEN * HDIM];      // 64 KB
    __shared__ _Float16 hF[2][HDIM];        // double-buffered h (f16 B source)
    __shared__ unsigned stepmask[QLEN];     // bit i set iff lwi[i]==s

    const int tid = threadIdx.x;
    const int wave = tid >> 6, lane = tid & 63;
    const int quad = lane >> 4, qr = lane & 15;
    const int myrow = 64 * wave + 16 * (qr >> 2) + quad * 4 + (qr & 3);

    #pragma unroll
    for (int i = 0; i < 16; i++) {
        int idx = (i * 256 + tid) * 4;
        *(float4*)(xpL + idx) = *(const float4*)(ws + WS_XP + idx);
    }
    if (tid < QLEN) {
        unsigned m = 0;
        #pragma unroll
        for (int i = 0; i < NNUM; i++) m |= (lwi[i] == tid) ? (1u << i) : 0u;
        stepmask[tid] = m;
    }
    const _Float16* wsh = (const _Float16*)(ws + WS_WH16);
    f16x8 aW[4][8];
    #pragma unroll
    for (int r = 0; r < 4; r++)
        #pragma unroll
        for (int kk = 0; kk < 8; kk++)
            aW[r][kk] = *(const f16x8*)(wsh + ((size_t)(((4 * wave + r) * 8 + kk) * 64 + lane)) * 8);
    #pragma unroll
    for (int r = 0; r < 4; r++)
        #pragma unroll
        for (int kk = 0; kk < 8; kk++) {
            f32x4 t = __builtin_bit_cast(f32x4, aW[r][kk]);
            asm volatile("" : "+v"(t));
            aW[r][kk] = __builtin_bit_cast(f16x8, t);
        }
    hF[0][tid] = (_Float16)0.f;
    __syncthreads();

    for (int s = 0; s < QLEN; s++) {
        const _Float16* hb = hF[s & 1];
        f16x8 bfrag[8];
        #pragma unroll
        for (int kk = 0; kk < 8; kk++)
            bfrag[kk] = *(const f16x8*)(hb + kk * 32 + quad * 8);   // broadcast read
        f32x4 acc[4];
        #pragma unroll
        for (int r = 0; r < 4; r++) acc[r] = (f32x4){0.f, 0.f, 0.f, 0.f};
        #pragma unroll
        for (int kk = 0; kk < 8; kk++)
            #pragma unroll
            for (int r = 0; r < 4; r++)   // 4 independent 8-deep chains
                acc[r] = __builtin_amdgcn_mfma_f32_16x16x32_f16(aW[r][kk], bfrag[kk], acc[r], 0, 0, 0);

        // parallel epilogue: lane (quad,qr) extracts tile r=qr>>2, elem qr&3
        f32x4 t01 = (qr & 4) ? acc[1] : acc[0];
        f32x4 t23 = (qr & 4) ? acc[3] : acc[2];
        f32x4 tt  = (qr & 8) ? t23 : t01;
        float e01 = (qr & 1) ? tt.y : tt.x;
        float e23 = (qr & 1) ? tt.w : tt.z;
        float v   = (qr & 2) ? e23 : e01;

        float h = fast_tanh(v + xpL[s * HDIM + myrow]);
        hF[(s + 1) & 1][myrow] = (_Float16)h;
        unsigned m = stepmask[s];
        while (m) {
            int i = __builtin_ctz(m);
            ws[WS_HS + i * HDIM + myrow] = h;
            m &= m - 1;
        }
        if (s == QLEN - 1) ws[WS_Q + myrow] = h;
        __syncthreads();                 // ONE barrier per step
    }
}

// ============================================================================
// Kernel P2: parallel q-projections.
// ============================================================================
__global__ void qproj_kernel(const float* __restrict__ W_op,
                             const float* __restrict__ W_col,
                             float* __restrict__ ws) {
    int gid = blockIdx.x * 256 + threadIdx.x;
    int dot = gid >> 5, l = gid & 31;
    int mat = dot >> 8, j = dot & 255;
    const float* w = (mat ? W_col : W_op) + (size_t)j * (2 * HDIM) + l * 8;
    const float* qv = ws + WS_Q + l * 8;
    float4 a0 = *(const float4*)w,        a1 = *(const float4*)(w + 4);
    float4 b0 = *(const float4*)qv,       b1 = *(const float4*)(qv + 4);
    float s = a0.x * b0.x + a0.y * b0.y + a0.z * b0.z + a0.w * b0.w
            + a1.x * b1.x + a1.y * b1.y + a1.z * b1.z + a1.w * b1.w;
    s += __shfl_xor(s, 1); s += __shfl_xor(s, 2); s += __shfl_xor(s, 4);
    s += __shfl_xor(s, 8); s += __shfl_xor(s, 16);
    if (l == 0) ws[(mat ? WS_PQC : WS_PQO) + j] = s;
}

// ============================================================================
// Kernel B2: single block, 256 threads — pivots + selector chain (T=4).
// ============================================================================
__global__ __launch_bounds__(256) void select_kernel(
        float* __restrict__ ws,
        const float* __restrict__ U,
        const int* __restrict__ nums,
        const float* __restrict__ op_emb,
        const float* __restrict__ col_emb) {
    __shared__ float zu[16];
    __shared__ float hH[HDIM];
    __shared__ float top_op[HDIM], top_col[HDIM], mh[HDIM];
    __shared__ float logits[32];
    __shared__ float aop_s[NOPS], acol_s[NCOLS];

    const int tid = threadIdx.x;

    {
        int g = tid >> 4, l = tid & 15;
        int i = g >> 1, u = g & 1;
        const float* z = ws + WS_HS + i * HDIM + l * 16;
        const float* uu = U + u * HDIM + l * 16;
        float s = 0.f;
        #pragma unroll
        for (int k = 0; k < 4; k++) {
            float4 a = *(const float4*)(z + k * 4), b = *(const float4*)(uu + k * 4);
            s += a.x * b.x + a.y * b.y + a.z * b.z + a.w * b.w;
        }
        s += __shfl_xor(s, 1); s += __shfl_xor(s, 2);
        s += __shfl_xor(s, 4); s += __shfl_xor(s, 8);
        if (l == 0) zu[g] = s;
    }
    if (tid < HDIM) hH[tid] = 0.f;
    __syncthreads();
    if (tid == 0) {
        #pragma unroll
        for (int u = 0; u < 2; u++) {
            float mx = -1e30f;
            for (int i = 0; i < NNUM; i++) mx = fmaxf(mx, zu[i * 2 + u]);
            float se = 0.f, pv = 0.f;
            for (int i = 0; i < NNUM; i++) {
                float e = __expf(zu[i * 2 + u] - mx);
                se += e;
                pv += e * (float)nums[i];
            }
            ws[u] = pv / se;
        }
    }
    __syncthreads();

    const _Float16* wsm = (const _Float16*)(ws + WS_M16);
    const float pqo = ws[WS_PQO + tid];
    const float pqc = ws[WS_PQC + tid];

    for (int t = 0; t < TSTEPS; t++) {
        float so = 0.f, sc = 0.f, sh = 0.f;
        #pragma unroll
        for (int i = 0; i < 32; i++) {
            float4 h0 = *(const float4*)(hH + i * 8);
            float4 h1 = *(const float4*)(hH + i * 8 + 4);
            f16x8 a = *(const f16x8*)(wsm + ((size_t)(0 * 32 + i) * 256 + tid) * 8);
            f16x8 b = *(const f16x8*)(wsm + ((size_t)(1 * 32 + i) * 256 + tid) * 8);
            f16x8 c = *(const f16x8*)(wsm + ((size_t)(2 * 32 + i) * 256 + tid) * 8);
            so += (float)a[0]*h0.x + (float)a[1]*h0.y + (float)a[2]*h0.z + (float)a[3]*h0.w
                + (float)a[4]*h1.x + (float)a[5]*h1.y + (float)a[6]*h1.z + (float)a[7]*h1.w;
            sc += (float)b[0]*h0.x + (float)b[1]*h0.y + (float)b[2]*h0.z + (float)b[3]*h0.w
                + (float)b[4]*h1.x + (float)b[5]*h1.y + (float)b[6]*h1.z + (float)b[7]*h1.w;
            sh += (float)c[0]*h0.x + (float)c[1]*h0.y + (float)c[2]*h0.z + (float)c[3]*h0.w
                + (float)c[4]*h1.x + (float)c[5]*h1.y + (float)c[6]*h1.z + (float)c[7]*h1.w;
        }
        top_op[tid]  = fast_tanh(pqo + so);
        top_col[tid] = fast_tanh(pqc + sc);
        mh[tid] = sh;
        __syncthreads();

        #pragma unroll
        for (int d0 = 0; d0 < 32; d0 += 8) {
            int d = d0 + (tid >> 5), l = tid & 31;
            if (d < 25) {
                float s = 0.f;
                if (d < NOPS) {
                    const float* e = op_emb + (size_t)d * HDIM;
                    #pragma unroll
                    for (int m = 0; m < 8; m++) s += e[l * 8 + m] * top_op[l * 8 + m];
                } else {
                    const float* e = col_emb + (size_t)(d - NOPS) * HDIM;
                    #pragma unroll
                    for (int m = 0; m < 8; m++) s += e[l * 8 + m] * top_col[l * 8 + m];
                }
                s += __shfl_xor(s, 1); s += __shfl_xor(s, 2); s += __shfl_xor(s, 4);
                s += __shfl_xor(s, 8); s += __shfl_xor(s, 16);
                if (l == 0) logits[d] = s;
            }
        }
        __syncthreads();
        if (tid == 0) {
            float mx = -1e30f;
            for (int o = 0; o < NOPS; o++) mx = fmaxf(mx, logits[o]);
            float se = 0.f, e[NOPS];
            for (int o = 0; o < NOPS; o++) { e[o] = __expf(logits[o] - mx); se += e[o]; }
            for (int o = 0; o < NOPS; o++) {
                float a = e[o] / se;
                aop_s[o] = a;
                ws[WS_AOP + t * NOPS + o] = a;
            }
        } else if (tid == 32) {
            float mx = -1e30f;
            for (int c = 0; c < NCOLS; c++) mx = fmaxf(mx, logits[NOPS + c]);
            float se = 0.f, e[NCOLS];
            for (int c = 0; c < NCOLS; c++) { e[c] = __expf(logits[NOPS + c] - mx); se += e[c]; }
            for (int c = 0; c < NCOLS; c++) {
                float a = e[c] / se;
                acol_s[c] = a;
                ws[WS_ACOL + t * NCOLS + c] = a;
            }
        }
        __syncthreads();
        {
            float s = mh[tid];
            const float* ah = ws + WS_AH + tid * NOPS;
            #pragma unroll
            for (int o = 0; o < NOPS; o++) s += ah[o] * aop_s[o];
            const float* bh = ws + WS_BH + tid * NCOLS;
            #pragma unroll
            for (int c = 0; c < NCOLS; c++) s += bh[c] * acol_s[c];
            float hv = fast_tanh(s);
            __syncthreads();
            hH[tid] = hv;
        }
        __syncthreads();
    }
}

// ============================================================================
// Kernel C: fused table pass — REWRITTEN 1-lane-per-row.
// Old scheme (4 lanes/row) duplicated the rs recursion x4 and spent 18
// shuffles/row: ~8 wave-ops/row. New: lane owns a full row (one 64-B cache
// line; the 4 offset loads L1-merge across the wave), computes all 16
// sigmoid pairs + pg/pl dots + the recursion once: ~4.2 wave-ops/row.
// Stores keep the old perfectly-coalesced pattern via an LDS transpose of
// the per-row weight wa (2 barriers per sweep iter; 2 iters total).
// Value-identical expressions; summation order differs (within tolerance).
// ============================================================================
__global__ __launch_bounds__(256) void table_kernel(
        const float* __restrict__ table,
        const float* __restrict__ wsc,
        float* __restrict__ wspart,
        float* __restrict__ out,
        int rows) {
    const int tid = threadIdx.x;
    const float lpiv = wsc[WS_LPIV];
    const float gpiv = wsc[WS_GPIV];
    // full acol for all 4 steps (uniform)
    float4 ac[TSTEPS][4];
    float wg[TSTEPS], wl[TSTEPS], wand[TSTEPS], wor[TSTEPS], wrst[TSTEPS], wpass[TSTEPS];
    #pragma unroll
    for (int t = 0; t < TSTEPS; t++) {
        #pragma unroll
        for (int g = 0; g < 4; g++)
            ac[t][g] = make_float4(wsc[WS_ACOL + t * NCOLS + g * 4 + 0],
                                   wsc[WS_ACOL + t * NCOLS + g * 4 + 1],
                                   wsc[WS_ACOL + t * NCOLS + g * 4 + 2],
                                   wsc[WS_ACOL + t * NCOLS + g * 4 + 3]);
        wg[t]   = wsc[WS_AOP + t * NOPS + 3];
        wl[t]   = wsc[WS_AOP + t * NOPS + 4];
        wand[t] = wsc[WS_AOP + t * NOPS + 5];
        wor[t]  = wsc[WS_AOP + t * NOPS + 6];
        wrst[t] = wsc[WS_AOP + t * NOPS + 8];
        wpass[t] = wsc[WS_AOP + t * NOPS + 0] + wsc[WS_AOP + t * NOPS + 1]
                 + wsc[WS_AOP + t * NOPS + 2] + wsc[WS_AOP + t * NOPS + 7];
    }
    const float wassign = wsc[WS_AOP + 3 * NOPS + 7];
    // acol[3] quad for this lane's STORE role (cq = tid&3), constant select
    const int cq = tid & 3;
    float4 a3s = (cq & 2) ? ((cq & 1) ? ac[3][3] : ac[3][2])
                          : ((cq & 1) ? ac[3][1] : ac[3][0]);

    __shared__ float waL[256];
    float dAcc[TSTEPS] = {0.f, 0.f, 0.f, 0.f};
    float nAcc[TSTEPS] = {0.f, 0.f, 0.f, 0.f};
    const long rowsL = rows;

    for (long r0 = (long)blockIdx.x * 256; r0 < rowsL; r0 += (long)NBLK_C * 256) {
        long row = r0 + tid;
        bool valid = row < rowsL;
        f32x4 tv0 = {0.f,0.f,0.f,0.f}, tv1 = tv0, tv2 = tv0, tv3 = tv0;
        if (valid) {
            const f32x4* tp = (const f32x4*)(table + row * NCOLS);
            tv0 = tp[0]; tv1 = tp[1]; tv2 = tp[2]; tv3 = tp[3];  // cached: one line/row
        }
        float prs = tv0.x+tv0.y+tv0.z+tv0.w + tv1.x+tv1.y+tv1.z+tv1.w
                  + tv2.x+tv2.y+tv2.z+tv2.w + tv3.x+tv3.y+tv3.z+tv3.w;
        float pg[TSTEPS] = {0.f,0.f,0.f,0.f};
        float pl[TSTEPS] = {0.f,0.f,0.f,0.f};
        #pragma unroll
        for (int g = 0; g < 4; g++) {
            f32x4 tv = (g == 0) ? tv0 : (g == 1) ? tv1 : (g == 2) ? tv2 : tv3;
            float c0 = tv.x, c1 = tv.y, c2 = tv.z, c3 = tv.w;
            float sg0 = __builtin_amdgcn_rcpf(1.f + __expf(gpiv - c0));
            float sg1 = __builtin_amdgcn_rcpf(1.f + __expf(gpiv - c1));
            float sg2 = __builtin_amdgcn_rcpf(1.f + __expf(gpiv - c2));
            float sg3 = __builtin_amdgcn_rcpf(1.f + __expf(gpiv - c3));
            float sl0 = __builtin_amdgcn_rcpf(1.f + __expf(c0 - lpiv));
            float sl1 = __builtin_amdgcn_rcpf(1.f + __expf(c1 - lpiv));
            float sl2 = __builtin_amdgcn_rcpf(1.f + __expf(c2 - lpiv));
            float sl3 = __builtin_amdgcn_rcpf(1.f + __expf(c3 - lpiv));
            #pragma unroll
            for (int t = 0; t < TSTEPS; t++) {
                pg[t] += sg0*ac[t][g].x + sg1*ac[t][g].y + sg2*ac[t][g].z + sg3*ac[t][g].w;
                pl[t] += sl0*ac[t][g].x + sl1*ac[t][g].y + sl2*ac[t][g].z + sl3*ac[t][g].w;
            }
        }
        float rs1 = 1.f, rs2 = 1.f;
        float vf = valid ? 1.f : 0.f;
        #pragma unroll
        for (int i = 0; i < TSTEPS; i++) {
            dAcc[i] += vf * rs1 * prs;
            nAcc[i] += vf * rs1;
            float nrs = wg[i] * pg[i] + wl[i] * pl[i]
                      + wand[i] * fminf(rs1, rs2) + wor[i] * fmaxf(rs1, rs2)
                      + wrst[i] + wpass[i] * rs1;
            rs2 = rs1;
            rs1 = nrs;
        }
        // LDS transpose of wa, then old-style coalesced stores (4 lanes/row)
        waL[tid] = vf * (wassign * rs1);
        __syncthreads();
        {
            int rq = tid >> 2;
            #pragma unroll
            for (int g = 0; g < 4; g++) {
                int lrow = g * 64 + rq;
                long row2 = r0 + lrow;
                if (row2 < rowsL) {
                    float wa2 = waL[lrow];
                    float* ob = out + 1 + row2 * NCOLS + cq * 4;
                    __builtin_nontemporal_store(wa2 * a3s.x, ob + 0);
                    __builtin_nontemporal_store(wa2 * a3s.y, ob + 1);
                    __builtin_nontemporal_store(wa2 * a3s.z, ob + 2);
                    __builtin_nontemporal_store(wa2 * a3s.w, ob + 3);
                }
            }
        }
        __syncthreads();   // before waL reuse next iteration
    }

    // block reduction of 8 partials (each row counted ONCE now — no 0.25)
    #pragma unroll
    for (int i = 0; i < TSTEPS; i++) {
        #pragma unroll
        for (int off = 32; off >= 1; off >>= 1) {
            dAcc[i] += __shfl_xor(dAcc[i], off);
            nAcc[i] += __shfl_xor(nAcc[i], off);
        }
    }
    __shared__ float redl[4][8];
    int wv = tid >> 6, ln = tid & 63;
    if (ln == 0) {
        #pragma unroll
        for (int i = 0; i < TSTEPS; i++) {
            redl[wv][i] = dAcc[i];
            redl[wv][4 + i] = nAcc[i];
        }
    }
    __syncthreads();
    if (tid < 8) {
        float s = redl[0][tid] + redl[1][tid] + redl[2][tid] + redl[3][tid];
        wspart[blockIdx.x * 8 + tid] = s;
    }
}

// ============================================================================
// Kernel D: reduce block partials, run the 4-step scalar recurrence
// ============================================================================
__global__ void finalize_kernel(const float* __restrict__ ws, float* __restrict__ out) {
    __shared__ float red[8];
    int a = threadIdx.x >> 5, l = threadIdx.x & 31;
    float s = 0.f;
    for (int b = l; b < NBLK_C; b += 32) s += ws[WS_PART + b * 8 + a];
    s += __shfl_xor(s, 1, 32); s += __shfl_xor(s, 2, 32); s += __shfl_xor(s, 4, 32);
    s += __shfl_xor(s, 8, 32); s += __shfl_xor(s, 16, 32);
    if (l == 0) red[a] = s;
    __syncthreads();
    if (threadIdx.x == 0) {
        float Dv[4] = {red[0], red[1], red[2], red[3]};
        float Nv[4] = {red[4], red[5], red[6], red[7]};
        const float* aop = ws + WS_AOP;
        float sc[5];
        sc[0] = 0.f;
        #pragma unroll
        for (int i = 0; i < 4; i++) {
            float s1 = sc[i];
            float s3 = sc[(i >= 2) ? (i - 2) : 0];
            sc[i + 1] = aop[i * NOPS + 0] * Dv[i] + aop[i * NOPS + 1] * Nv[i]
                      + aop[i * NOPS + 2] * (s3 - s1);
        }
        out[0] = sc[4];
    }
}

// ============================================================================
extern "C" void kernel_launch(void* const* d_in, const int* in_sizes, int n_in,
                              void* d_out, int out_size, void* d_ws, size_t ws_size,
                              hipStream_t stream) {
    const int*   q       = (const int*)d_in[0];
    const int*   nums    = (const int*)d_in[1];
    const int*   lwi     = (const int*)d_in[2];
    const float* table   = (const float*)d_in[3];
    const float* emb     = (const float*)d_in[4];
    const float* Wx      = (const float*)d_in[5];
    const float* Wh      = (const float*)d_in[6];
    const float* W_op    = (const float*)d_in[7];
    const float* op_emb  = (const float*)d_in[8];
    const float* W_col   = (const float*)d_in[9];
    const float* col_emb = (const float*)d_in[10];
    const float* W_hist  = (const float*)d_in[11];
    const float* U       = (const float*)d_in[12];
    float* out = (float*)d_out;
    float* ws  = (float*)d_ws;
    int rows = in_sizes[3] / NCOLS;

    // part 1: xproj (16384) + FULL Wh pack (32768 dwords) = 49152 threads
    precompute_kernel<<<192, 256, 0, stream>>>(q, emb, Wx, Wh, ws);
    // block 0: RNN; blocks 1..409: AH/BH/M16 pack; blocks 410..2457: L3 warm
    rnn_kernel<<<1 + PRE2_BLOCKS + 2048, 256, 0, stream>>>(
        ws, lwi, W_op, W_col, W_hist, op_emb, col_emb, table, rows);
    qproj_kernel<<<64, 256, 0, stream>>>(W_op, W_col, ws);
    select_kernel<<<1, 256, 0, stream>>>(ws, U, nums, op_emb, col_emb);
    table_kernel<<<NBLK_C, 256, 0, stream>>>(
        table, ws, ws + WS_PART, out, rows);
    finalize_kernel<<<1, 256, 0, stream>>>(ws, out);
}

// Round 7
// 257.395 us; speedup vs baseline: 1.0930x; 1.0930x over previous
//
#include <hip/hip_runtime.h>
#include <hip/hip_fp16.h>
#include <math.h>

#define HDIM   256
#define QLEN   64
#define NNUM   8
#define NOPS   9
#define NCOLS  16
#define TSTEPS 4

// op indices: SUM=0 COUNT=1 DIFF=2 GREATER=3 LESSER=4 AND=5 OR=6 ASSIGN=7 RESET=8

// ---- workspace layout (float offsets) ----
#define WS_LPIV 0
#define WS_GPIV 1
#define WS_ACOL 2            // [4][16]
#define WS_AOP  66           // [4][9]
#define WS_Q    112          // [256] final question RNN state q
#define WS_PQO  368          // [256] W_op[:, :256] @ q
#define WS_PQC  624          // [256] W_col[:, :256] @ q
#define WS_HS   880          // [8][256] hidden states at left_word_indices
#define WS_XP   2928         // [64][256] xproj
#define WS_AH   19312        // [256][9]  W_hist[:, :256] @ op_emb.T
#define WS_BH   21616        // [256][16] W_hist[:, 256:512] @ col_emb.T
#define WS_WH16 25712        // Wh as f16, fragment order (65536 halfs = 32768 f)
#define WS_M16  58480        // 3x 256x256 f16 (h-side of W_op/W_col/W_hist): 98304 floats
#define WS_PART 156784       // [NBLK_C][8] block partials (D0..3, N0..3)
#define NBLK_C  2048
#define PRE2_BLOCKS 409      // ceil(104704/256)

typedef _Float16 f16x8 __attribute__((ext_vector_type(8)));
typedef _Float16 f16x4 __attribute__((ext_vector_type(4)));
typedef float    f32x4 __attribute__((ext_vector_type(4)));

__device__ __forceinline__ float fast_tanh(float x) {
    return 1.0f - 2.0f / (__expf(2.0f * x) + 1.0f);
}

// ============================================================================
// Kernel A (part 1): what the RNN needs — xproj + FULL Wh f16 pack.
//  gid ranges:
//   [0, 16384)              xproj[t][j] = emb[q[t]] . Wx[j,:]
//   [16384, 49152)          Wh -> f16 fragment-order pack, 32768 dwords,
//                           ALL 256 rows (tile t=hidx>>12 in [0,16))
// ============================================================================
__global__ void precompute_kernel(const int* __restrict__ q,
                                  const float* __restrict__ emb,
                                  const float* __restrict__ Wx,
                                  const float* __restrict__ Wh,
                                  float* __restrict__ ws) {
    int gid = blockIdx.x * 256 + threadIdx.x;
    if (gid < QLEN * HDIM) {
        int t = gid >> 8, j = gid & 255;
        const float4* x4 = (const float4*)(emb + (size_t)q[t] * HDIM);
        const float4* w4 = (const float4*)(Wx + (size_t)j * HDIM);
        float s = 0.f;
        for (int k = 0; k < HDIM / 4; k++) {
            float4 a = x4[k], b = w4[k];
            s += a.x * b.x + a.y * b.y + a.z * b.z + a.w * b.w;
        }
        ws[WS_XP + t * HDIM + j] = s;
    } else {
        // Wh f16 pack: half-index = (((t*8+kk)*4+quad)*16+qr)*8 + e,
        // value = Wh[16*t+qr][kk*32 + quad*8 + e], t in [0,16) (ALL rows)
        int did = gid - QLEN * HDIM;       // [0, 32768) dwords
        int hidx = did * 2;
        int e = hidx & 7, qr = (hidx >> 3) & 15, quad = (hidx >> 7) & 3;
        int kk = (hidx >> 9) & 7, t = hidx >> 12;
        const float* src = Wh + (size_t)(16 * t + qr) * HDIM + kk * 32 + quad * 8 + e;
        float2 v = *(const float2*)src;
        ((__half2*)(ws + WS_WH16))[did] = __floats2half2_rn(v.x, v.y);
    }
}

// ============================================================================
// Kernel B1: block 0 = question RNN (one-barrier body). Blocks 1..409 =
// AH/BH/M16 precompute (disjoint ws regions). Blocks 410..2457 = L3 warm of
// `table` (r6: verified — table_kernel FETCH dropped 64->40 MB).
// ============================================================================
__global__ __launch_bounds__(256, 1) void rnn_kernel(
        float* __restrict__ ws,
        const int* __restrict__ lwi,
        const float* __restrict__ W_op,
        const float* __restrict__ W_col,
        const float* __restrict__ W_hist,
        const float* __restrict__ op_emb,
        const float* __restrict__ col_emb,
        const float* __restrict__ table,
        int rows) {
    if (blockIdx.x >= 1 + PRE2_BLOCKS) {
        // ---- L3 warm: stream table (cached loads, coalesced) ----
        int wid = blockIdx.x - 1 - PRE2_BLOCKS;          // 0..2047
        const f32x4* t4 = (const f32x4*)table;
        long n4 = (long)rows * (NCOLS / 4);
        f32x4 acc = {0.f, 0.f, 0.f, 0.f};
        for (long i = (long)wid * 256 + threadIdx.x; i < n4; i += (long)2048 * 256)
            acc += t4[i];
        asm volatile("" :: "v"(acc));                    // sink (no DCE)
        return;
    }
    if (blockIdx.x != 0) {
        // ---- fused precompute part 2 ----
        int gid = (blockIdx.x - 1) * 256 + threadIdx.x;
        if (gid < HDIM * NOPS) {
            int j = gid / NOPS, o = gid % NOPS;
            const float4* w4 = (const float4*)(W_hist + (size_t)j * (3 * HDIM));
            const float4* e4 = (const float4*)(op_emb + (size_t)o * HDIM);
            float s = 0.f;
            for (int k = 0; k < HDIM / 4; k++) {
                float4 a = w4[k], b = e4[k];
                s += a.x * b.x + a.y * b.y + a.z * b.z + a.w * b.w;
            }
            ws[WS_AH + gid] = s;
        } else if (gid < HDIM * NOPS + HDIM * NCOLS) {
            int idx = gid - HDIM * NOPS;
            int j = idx / NCOLS, c = idx % NCOLS;
            const float4* w4 = (const float4*)(W_hist + (size_t)j * (3 * HDIM) + HDIM);
            const float4* e4 = (const float4*)(col_emb + (size_t)c * HDIM);
            float s = 0.f;
            for (int k = 0; k < HDIM / 4; k++) {
                float4 a = w4[k], b = e4[k];
                s += a.x * b.x + a.y * b.y + a.z * b.z + a.w * b.w;
            }
            ws[WS_BH + idx] = s;
        } else if (gid < HDIM * NOPS + HDIM * NCOLS + 98304) {
            // M16 pack: mat m = did>>15, within-mat half-index = (i*256+j)*8+e
            int did = gid - (HDIM * NOPS + HDIM * NCOLS);
            int mat = did >> 15;
            int hidx = (did & 32767) * 2;
            int e = hidx & 7, j = (hidx >> 3) & 255, i = hidx >> 11;
            const float* src;
            if (mat == 0)      src = W_op   + (size_t)j * (2 * HDIM) + HDIM     + i * 8 + e;
            else if (mat == 1) src = W_col  + (size_t)j * (2 * HDIM) + HDIM     + i * 8 + e;
            else               src = W_hist + (size_t)j * (3 * HDIM) + 2 * HDIM + i * 8 + e;
            float2 v = *(const float2*)src;
            ((__half2*)(ws + WS_M16))[did] = __floats2half2_rn(v.x, v.y);
        }
        return;
    }

    // ---- block 0: the RNN (one-barrier body, unchanged) ----
    __shared__ float xpL[QLEN * HDIM];      // 64 KB
    __shared__ _Float16 hF[2][HDIM];        // double-buffered h (f16 B source)
    __shared__ unsigned stepmask[QLEN];     // bit i set iff lwi[i]==s

    const int tid = threadIdx.x;
    const int wave = tid >> 6, lane = tid & 63;
    const int quad = lane >> 4, qr = lane & 15;
    const int myrow = 64 * wave + 16 * (qr >> 2) + quad * 4 + (qr & 3);

    #pragma unroll
    for (int i = 0; i < 16; i++) {
        int idx = (i * 256 + tid) * 4;
        *(float4*)(xpL + idx) = *(const float4*)(ws + WS_XP + idx);
    }
    if (tid < QLEN) {
        unsigned m = 0;
        #pragma unroll
        for (int i = 0; i < NNUM; i++) m |= (lwi[i] == tid) ? (1u << i) : 0u;
        stepmask[tid] = m;
    }
    const _Float16* wsh = (const _Float16*)(ws + WS_WH16);
    f16x8 aW[4][8];
    #pragma unroll
    for (int r = 0; r < 4; r++)
        #pragma unroll
        for (int kk = 0; kk < 8; kk++)
            aW[r][kk] = *(const f16x8*)(wsh + ((size_t)(((4 * wave + r) * 8 + kk) * 64 + lane)) * 8);
    #pragma unroll
    for (int r = 0; r < 4; r++)
        #pragma unroll
        for (int kk = 0; kk < 8; kk++) {
            f32x4 t = __builtin_bit_cast(f32x4, aW[r][kk]);
            asm volatile("" : "+v"(t));
            aW[r][kk] = __builtin_bit_cast(f16x8, t);
        }
    hF[0][tid] = (_Float16)0.f;
    __syncthreads();

    for (int s = 0; s < QLEN; s++) {
        const _Float16* hb = hF[s & 1];
        f16x8 bfrag[8];
        #pragma unroll
        for (int kk = 0; kk < 8; kk++)
            bfrag[kk] = *(const f16x8*)(hb + kk * 32 + quad * 8);   // broadcast read
        f32x4 acc[4];
        #pragma unroll
        for (int r = 0; r < 4; r++) acc[r] = (f32x4){0.f, 0.f, 0.f, 0.f};
        #pragma unroll
        for (int kk = 0; kk < 8; kk++)
            #pragma unroll
            for (int r = 0; r < 4; r++)   // 4 independent 8-deep chains
                acc[r] = __builtin_amdgcn_mfma_f32_16x16x32_f16(aW[r][kk], bfrag[kk], acc[r], 0, 0, 0);

        // parallel epilogue: lane (quad,qr) extracts tile r=qr>>2, elem qr&3
        f32x4 t01 = (qr & 4) ? acc[1] : acc[0];
        f32x4 t23 = (qr & 4) ? acc[3] : acc[2];
        f32x4 tt  = (qr & 8) ? t23 : t01;
        float e01 = (qr & 1) ? tt.y : tt.x;
        float e23 = (qr & 1) ? tt.w : tt.z;
        float v   = (qr & 2) ? e23 : e01;

        float h = fast_tanh(v + xpL[s * HDIM + myrow]);
        hF[(s + 1) & 1][myrow] = (_Float16)h;
        unsigned m = stepmask[s];
        while (m) {
            int i = __builtin_ctz(m);
            ws[WS_HS + i * HDIM + myrow] = h;
            m &= m - 1;
        }
        if (s == QLEN - 1) ws[WS_Q + myrow] = h;
        __syncthreads();                 // ONE barrier per step
    }
}

// ============================================================================
// Kernel P2: parallel q-projections.
// ============================================================================
__global__ void qproj_kernel(const float* __restrict__ W_op,
                             const float* __restrict__ W_col,
                             float* __restrict__ ws) {
    int gid = blockIdx.x * 256 + threadIdx.x;
    int dot = gid >> 5, l = gid & 31;
    int mat = dot >> 8, j = dot & 255;
    const float* w = (mat ? W_col : W_op) + (size_t)j * (2 * HDIM) + l * 8;
    const float* qv = ws + WS_Q + l * 8;
    float4 a0 = *(const float4*)w,        a1 = *(const float4*)(w + 4);
    float4 b0 = *(const float4*)qv,       b1 = *(const float4*)(qv + 4);
    float s = a0.x * b0.x + a0.y * b0.y + a0.z * b0.z + a0.w * b0.w
            + a1.x * b1.x + a1.y * b1.y + a1.z * b1.z + a1.w * b1.w;
    s += __shfl_xor(s, 1); s += __shfl_xor(s, 2); s += __shfl_xor(s, 4);
    s += __shfl_xor(s, 8); s += __shfl_xor(s, 16);
    if (l == 0) ws[(mat ? WS_PQC : WS_PQO) + j] = s;
}

// ============================================================================
// Kernel B2: single block, 256 threads — pivots + selector chain (T=4).
// ============================================================================
__global__ __launch_bounds__(256) void select_kernel(
        float* __restrict__ ws,
        const float* __restrict__ U,
        const int* __restrict__ nums,
        const float* __restrict__ op_emb,
        const float* __restrict__ col_emb) {
    __shared__ float zu[16];
    __shared__ float hH[HDIM];
    __shared__ float top_op[HDIM], top_col[HDIM], mh[HDIM];
    __shared__ float logits[32];
    __shared__ float aop_s[NOPS], acol_s[NCOLS];

    const int tid = threadIdx.x;

    {
        int g = tid >> 4, l = tid & 15;
        int i = g >> 1, u = g & 1;
        const float* z = ws + WS_HS + i * HDIM + l * 16;
        const float* uu = U + u * HDIM + l * 16;
        float s = 0.f;
        #pragma unroll
        for (int k = 0; k < 4; k++) {
            float4 a = *(const float4*)(z + k * 4), b = *(const float4*)(uu + k * 4);
            s += a.x * b.x + a.y * b.y + a.z * b.z + a.w * b.w;
        }
        s += __shfl_xor(s, 1); s += __shfl_xor(s, 2);
        s += __shfl_xor(s, 4); s += __shfl_xor(s, 8);
        if (l == 0) zu[g] = s;
    }
    if (tid < HDIM) hH[tid] = 0.f;
    __syncthreads();
    if (tid == 0) {
        #pragma unroll
        for (int u = 0; u < 2; u++) {
            float mx = -1e30f;
            for (int i = 0; i < NNUM; i++) mx = fmaxf(mx, zu[i * 2 + u]);
            float se = 0.f, pv = 0.f;
            for (int i = 0; i < NNUM; i++) {
                float e = __expf(zu[i * 2 + u] - mx);
                se += e;
                pv += e * (float)nums[i];
            }
            ws[u] = pv / se;
        }
    }
    __syncthreads();

    const _Float16* wsm = (const _Float16*)(ws + WS_M16);
    const float pqo = ws[WS_PQO + tid];
    const float pqc = ws[WS_PQC + tid];

    for (int t = 0; t < TSTEPS; t++) {
        float so = 0.f, sc = 0.f, sh = 0.f;
        #pragma unroll
        for (int i = 0; i < 32; i++) {
            float4 h0 = *(const float4*)(hH + i * 8);
            float4 h1 = *(const float4*)(hH + i * 8 + 4);
            f16x8 a = *(const f16x8*)(wsm + ((size_t)(0 * 32 + i) * 256 + tid) * 8);
            f16x8 b = *(const f16x8*)(wsm + ((size_t)(1 * 32 + i) * 256 + tid) * 8);
            f16x8 c = *(const f16x8*)(wsm + ((size_t)(2 * 32 + i) * 256 + tid) * 8);
            so += (float)a[0]*h0.x + (float)a[1]*h0.y + (float)a[2]*h0.z + (float)a[3]*h0.w
                + (float)a[4]*h1.x + (float)a[5]*h1.y + (float)a[6]*h1.z + (float)a[7]*h1.w;
            sc += (float)b[0]*h0.x + (float)b[1]*h0.y + (float)b[2]*h0.z + (float)b[3]*h0.w
                + (float)b[4]*h1.x + (float)b[5]*h1.y + (float)b[6]*h1.z + (float)b[7]*h1.w;
            sh += (float)c[0]*h0.x + (float)c[1]*h0.y + (float)c[2]*h0.z + (float)c[3]*h0.w
                + (float)c[4]*h1.x + (float)c[5]*h1.y + (float)c[6]*h1.z + (float)c[7]*h1.w;
        }
        top_op[tid]  = fast_tanh(pqo + so);
        top_col[tid] = fast_tanh(pqc + sc);
        mh[tid] = sh;
        __syncthreads();

        #pragma unroll
        for (int d0 = 0; d0 < 32; d0 += 8) {
            int d = d0 + (tid >> 5), l = tid & 31;
            if (d < 25) {
                float s = 0.f;
                if (d < NOPS) {
                    const float* e = op_emb + (size_t)d * HDIM;
                    #pragma unroll
                    for (int m = 0; m < 8; m++) s += e[l * 8 + m] * top_op[l * 8 + m];
                } else {
                    const float* e = col_emb + (size_t)(d - NOPS) * HDIM;
                    #pragma unroll
                    for (int m = 0; m < 8; m++) s += e[l * 8 + m] * top_col[l * 8 + m];
                }
                s += __shfl_xor(s, 1); s += __shfl_xor(s, 2); s += __shfl_xor(s, 4);
                s += __shfl_xor(s, 8); s += __shfl_xor(s, 16);
                if (l == 0) logits[d] = s;
            }
        }
        __syncthreads();
        if (tid == 0) {
            float mx = -1e30f;
            for (int o = 0; o < NOPS; o++) mx = fmaxf(mx, logits[o]);
            float se = 0.f, e[NOPS];
            for (int o = 0; o < NOPS; o++) { e[o] = __expf(logits[o] - mx); se += e[o]; }
            for (int o = 0; o < NOPS; o++) {
                float a = e[o] / se;
                aop_s[o] = a;
                ws[WS_AOP + t * NOPS + o] = a;
            }
        } else if (tid == 32) {
            float mx = -1e30f;
            for (int c = 0; c < NCOLS; c++) mx = fmaxf(mx, logits[NOPS + c]);
            float se = 0.f, e[NCOLS];
            for (int c = 0; c < NCOLS; c++) { e[c] = __expf(logits[NOPS + c] - mx); se += e[c]; }
            for (int c = 0; c < NCOLS; c++) {
                float a = e[c] / se;
                acol_s[c] = a;
                ws[WS_ACOL + t * NCOLS + c] = a;
            }
        }
        __syncthreads();
        {
            float s = mh[tid];
            const float* ah = ws + WS_AH + tid * NOPS;
            #pragma unroll
            for (int o = 0; o < NOPS; o++) s += ah[o] * aop_s[o];
            const float* bh = ws + WS_BH + tid * NCOLS;
            #pragma unroll
            for (int c = 0; c < NCOLS; c++) s += bh[c] * acol_s[c];
            float hv = fast_tanh(s);
            __syncthreads();
            hH[tid] = hv;
        }
        __syncthreads();
    }
}

// ============================================================================
// Kernel C: fused table pass — round-5 4-lanes/row body (proven coalesced
// loads) with ONE change: stores are PLAIN dwords (through L2), not
// nontemporal. r6 counters showed nt dword stores at the +1-offset layout
// cost 195 MB of HBM writes for a 64 MB output (3x amplification, 80% of
// the kernel's traffic): nt streams partial 64-B lines to DRAM. Plain
// stores let L2 assemble full dirty lines (the wave's stores tile a
// contiguous 1-KB span) and evict each line once.
// ============================================================================
__global__ __launch_bounds__(256) void table_kernel(
        const float* __restrict__ table,
        const float* __restrict__ wsc,
        float* __restrict__ wspart,
        float* __restrict__ out,
        int rows) {
    const int tid = threadIdx.x;
    const int cq = tid & 3;
    const float lpiv = wsc[WS_LPIV];
    const float gpiv = wsc[WS_GPIV];
    float4 acol4[TSTEPS];
    float wg[TSTEPS], wl[TSTEPS], wand[TSTEPS], wor[TSTEPS], wrst[TSTEPS], wpass[TSTEPS];
    #pragma unroll
    for (int t = 0; t < TSTEPS; t++) {
        acol4[t] = make_float4(wsc[WS_ACOL + t * NCOLS + cq * 4 + 0],
                               wsc[WS_ACOL + t * NCOLS + cq * 4 + 1],
                               wsc[WS_ACOL + t * NCOLS + cq * 4 + 2],
                               wsc[WS_ACOL + t * NCOLS + cq * 4 + 3]);
        wg[t]   = wsc[WS_AOP + t * NOPS + 3];
        wl[t]   = wsc[WS_AOP + t * NOPS + 4];
        wand[t] = wsc[WS_AOP + t * NOPS + 5];
        wor[t]  = wsc[WS_AOP + t * NOPS + 6];
        wrst[t] = wsc[WS_AOP + t * NOPS + 8];
        wpass[t] = wsc[WS_AOP + t * NOPS + 0] + wsc[WS_AOP + t * NOPS + 1]
                 + wsc[WS_AOP + t * NOPS + 2] + wsc[WS_AOP + t * NOPS + 7];
    }
    const float wassign = wsc[WS_AOP + 3 * NOPS + 7];

    float dAcc[TSTEPS] = {0.f, 0.f, 0.f, 0.f};
    float nAcc[TSTEPS] = {0.f, 0.f, 0.f, 0.f};
    const long rowsL = rows;

    for (long r0 = (long)blockIdx.x * 64; r0 < rowsL; r0 += (long)NBLK_C * 64) {
        long row = r0 + (tid >> 2);
        bool valid = row < rowsL;
        f32x4 tv = {0.f, 0.f, 0.f, 0.f};
        if (valid)
            tv = __builtin_nontemporal_load((const f32x4*)(table + row * NCOLS + cq * 4));
        float prs = tv.x + tv.y + tv.z + tv.w;
        float pg[4], pl[4];
        {
            float c0 = tv.x, c1 = tv.y, c2 = tv.z, c3 = tv.w;
            float sg0 = __builtin_amdgcn_rcpf(1.f + __expf(gpiv - c0));
            float sg1 = __builtin_amdgcn_rcpf(1.f + __expf(gpiv - c1));
            float sg2 = __builtin_amdgcn_rcpf(1.f + __expf(gpiv - c2));
            float sg3 = __builtin_amdgcn_rcpf(1.f + __expf(gpiv - c3));
            float sl0 = __builtin_amdgcn_rcpf(1.f + __expf(c0 - lpiv));
            float sl1 = __builtin_amdgcn_rcpf(1.f + __expf(c1 - lpiv));
            float sl2 = __builtin_amdgcn_rcpf(1.f + __expf(c2 - lpiv));
            float sl3 = __builtin_amdgcn_rcpf(1.f + __expf(c3 - lpiv));
            #pragma unroll
            for (int t = 0; t < TSTEPS; t++) {
                pg[t] = sg0 * acol4[t].x + sg1 * acol4[t].y + sg2 * acol4[t].z + sg3 * acol4[t].w;
                pl[t] = sl0 * acol4[t].x + sl1 * acol4[t].y + sl2 * acol4[t].z + sl3 * acol4[t].w;
            }
        }
        // reduce over the 4 lanes of this row (lanes differ in low 2 bits)
        prs += __shfl_xor(prs, 1); prs += __shfl_xor(prs, 2);
        #pragma unroll
        for (int t = 0; t < TSTEPS; t++) {
            pg[t] += __shfl_xor(pg[t], 1); pg[t] += __shfl_xor(pg[t], 2);
            pl[t] += __shfl_xor(pl[t], 1); pl[t] += __shfl_xor(pl[t], 2);
        }
        float rs1 = 1.f, rs2 = 1.f;
        float vf = valid ? 1.f : 0.f;
        #pragma unroll
        for (int i = 0; i < TSTEPS; i++) {
            dAcc[i] += vf * rs1 * prs;
            nAcc[i] += vf * rs1;
            float nrs = wg[i] * pg[i] + wl[i] * pl[i]
                      + wand[i] * fminf(rs1, rs2) + wor[i] * fmaxf(rs1, rs2)
                      + wrst[i] + wpass[i] * rs1;
            rs2 = rs1;
            rs1 = nrs;
        }
        if (valid) {
            float wa = wassign * rs1;   // rs^(4)
            float* ob = out + 1 + row * NCOLS + cq * 4;
            ob[0] = wa * acol4[3].x;    // plain stores: combine in L2,
            ob[1] = wa * acol4[3].y;    // full-line eviction (no nt
            ob[2] = wa * acol4[3].z;    // partial-line streaming)
            ob[3] = wa * acol4[3].w;
        }
    }

    // block reduction of 8 partials (each row counted 4x -> scale 0.25)
    #pragma unroll
    for (int i = 0; i < TSTEPS; i++) {
        #pragma unroll
        for (int off = 32; off >= 1; off >>= 1) {
            dAcc[i] += __shfl_xor(dAcc[i], off);
            nAcc[i] += __shfl_xor(nAcc[i], off);
        }
    }
    __shared__ float redl[4][8];
    int wv = tid >> 6, ln = tid & 63;
    if (ln == 0) {
        #pragma unroll
        for (int i = 0; i < TSTEPS; i++) {
            redl[wv][i] = dAcc[i];
            redl[wv][4 + i] = nAcc[i];
        }
    }
    __syncthreads();
    if (tid < 8) {
        float s = redl[0][tid] + redl[1][tid] + redl[2][tid] + redl[3][tid];
        wspart[blockIdx.x * 8 + tid] = 0.25f * s;
    }
}

// ============================================================================
// Kernel D: reduce block partials, run the 4-step scalar recurrence
// ============================================================================
__global__ void finalize_kernel(const float* __restrict__ ws, float* __restrict__ out) {
    __shared__ float red[8];
    int a = threadIdx.x >> 5, l = threadIdx.x & 31;
    float s = 0.f;
    for (int b = l; b < NBLK_C; b += 32) s += ws[WS_PART + b * 8 + a];
    s += __shfl_xor(s, 1, 32); s += __shfl_xor(s, 2, 32); s += __shfl_xor(s, 4, 32);
    s += __shfl_xor(s, 8, 32); s += __shfl_xor(s, 16, 32);
    if (l == 0) red[a] = s;
    __syncthreads();
    if (threadIdx.x == 0) {
        float Dv[4] = {red[0], red[1], red[2], red[3]};
        float Nv[4] = {red[4], red[5], red[6], red[7]};
        const float* aop = ws + WS_AOP;
        float sc[5];
        sc[0] = 0.f;
        #pragma unroll
        for (int i = 0; i < 4; i++) {
            float s1 = sc[i];
            float s3 = sc[(i >= 2) ? (i - 2) : 0];
            sc[i + 1] = aop[i * NOPS + 0] * Dv[i] + aop[i * NOPS + 1] * Nv[i]
                      + aop[i * NOPS + 2] * (s3 - s1);
        }
        out[0] = sc[4];
    }
}

// ============================================================================
extern "C" void kernel_launch(void* const* d_in, const int* in_sizes, int n_in,
                              void* d_out, int out_size, void* d_ws, size_t ws_size,
                              hipStream_t stream) {
    const int*   q       = (const int*)d_in[0];
    const int*   nums    = (const int*)d_in[1];
    const int*   lwi     = (const int*)d_in[2];
    const float* table   = (const float*)d_in[3];
    const float* emb     = (const float*)d_in[4];
    const float* Wx      = (const float*)d_in[5];
    const float* Wh      = (const float*)d_in[6];
    const float* W_op    = (const float*)d_in[7];
    const float* op_emb  = (const float*)d_in[8];
    const float* W_col   = (const float*)d_in[9];
    const float* col_emb = (const float*)d_in[10];
    const float* W_hist  = (const float*)d_in[11];
    const float* U       = (const float*)d_in[12];
    float* out = (float*)d_out;
    float* ws  = (float*)d_ws;
    int rows = in_sizes[3] / NCOLS;

    // part 1: xproj (16384) + FULL Wh pack (32768 dwords) = 49152 threads
    precompute_kernel<<<192, 256, 0, stream>>>(q, emb, Wx, Wh, ws);
    // block 0: RNN; blocks 1..409: AH/BH/M16 pack; blocks 410..2457: L3 warm
    rnn_kernel<<<1 + PRE2_BLOCKS + 2048, 256, 0, stream>>>(
        ws, lwi, W_op, W_col, W_hist, op_emb, col_emb, table, rows);
    qproj_kernel<<<64, 256, 0, stream>>>(W_op, W_col, ws);
    select_kernel<<<1, 256, 0, stream>>>(ws, U, nums, op_emb, col_emb);
    table_kernel<<<NBLK_C, 256, 0, stream>>>(
        table, ws, ws + WS_PART, out, rows);
    finalize_kernel<<<1, 256, 0, stream>>>(ws, out);
}